// Round 6
// baseline (466.678 us; speedup 1.0000x reference)
//
#include <hip/hip_runtime.h>

#define BS 1024
#define D 128
#define NC 100000
#define NCP 106496           /* padded to 832*128 so every block runs exactly 13 tiles */
#define NPAD 6496.0f         /* pad columns, each contributes exactly exp2(0)=1 raw */
#define S_SCALE 30.0f
#define MARGIN 0.35f
#define GRIDX 64             /* 64*8 = 512 blocks; XCD = x%8 -> B-phase L2 locality */
#define GRID_TOTAL (GRIDX * 8)
#define TILES_PER_BLOCK 13
#define C_EXP 43.280851226668917f   /* 30 * log2(e); A prescaled by this */

typedef __attribute__((ext_vector_type(8))) short bf16x8;
typedef __attribute__((ext_vector_type(4))) float f32x4;

__device__ __forceinline__ unsigned short f2bf(float f) {
    union { float f; unsigned u; } x; x.f = f;
    unsigned u = x.u;
    u += 0x7FFFu + ((u >> 16) & 1u);   // round-to-nearest-even
    return (unsigned short)(u >> 16);
}

__device__ __forceinline__ float fast_exp2(float x) {
#if __has_builtin(__builtin_amdgcn_exp2f)
    return __builtin_amdgcn_exp2f(x);
#else
    return exp2f(x);
#endif
}

// One wave per input row (4 rows/block): l2-normalize, emit prescaled PLAIN
// row-major bf16, exact-f32 pos (in e-units: pos = 30*cos), counts, and
// segment-sum into acc[claimer_row].
__global__ void prep_fn(const float* __restrict__ inp, const int* __restrict__ label,
                        const float* __restrict__ wt,
                        unsigned short* __restrict__ fnb,
                        float* __restrict__ counts, int* __restrict__ class2slot,
                        float* __restrict__ acc, float* __restrict__ pos) {
    int wv = threadIdx.x >> 6, lane = threadIdx.x & 63;
    int row = blockIdx.x * 4 + wv;     // grid 256 -> 1024 rows
    int c = label[row];
    float2 v   = *(const float2*)(inp + row * D + lane * 2);
    float2 wv2 = *(const float2*)(wt + c * D + lane * 2);

    float s = v.x * v.x + v.y * v.y;
    #pragma unroll
    for (int m = 1; m < 64; m <<= 1) s += __shfl_xor(s, m);
    float inv = 1.0f / fmaxf(sqrtf(s), 1e-12f);
    float a = v.x * inv, b = v.y * inv;

    // plain row-major prescaled bf16 (A[row][k], k-contiguous)
    unsigned pack = (unsigned)f2bf(a * C_EXP) | ((unsigned)f2bf(b * C_EXP) << 16);
    ((unsigned*)fnb)[row * 64 + lane] = pack;

    // pos: exact f32 cosine with the label's normalized weight row
    float sw_ = wv2.x * wv2.x + wv2.y * wv2.y;
    float dt  = wv2.x * a + wv2.y * b;
    #pragma unroll
    for (int m = 1; m < 64; m <<= 1) { sw_ += __shfl_xor(sw_, m); dt += __shfl_xor(dt, m); }

    int slotrow = 0;
    if (lane == 0) {
        pos[row] = S_SCALE * dt * (1.0f / fmaxf(sqrtf(sw_), 1e-12f));
        atomicAdd(counts + c, 1.0f);
        int prev = atomicCAS(class2slot + c, 0, row + 1);
        slotrow = prev ? (prev - 1) : row;
    }
    slotrow = __shfl(slotrow, 0);
    atomicAdd(acc + slotrow * D + lane * 2,     a);
    atomicAdd(acc + slotrow * D + lane * 2 + 1, b);
}

// 8 rows/block, 32 lanes/row, float4 loads: l2-normalize -> PLAIN row-major
// bf16 wn (no swizzle; gemm loads fragments direct from global). Pad rows -> 0.
// Fused weight output: present class -> mean (acc/cnt), absent -> copy.
__global__ void prep_wn(const float* __restrict__ wt, const float* __restrict__ counts,
                        const int* __restrict__ class2slot, const float* __restrict__ acc,
                        unsigned short* __restrict__ wnb, float* __restrict__ outw) {
    int t = threadIdx.x;
    int row = blockIdx.x * 8 + (t >> 5);   // grid 13312 -> 106496 incl. pad
    int l = t & 31;
    uint2* dst = (uint2*)(wnb + row * D + l * 4);
    if (row < NC) {
        float4 v = *(const float4*)(wt + row * D + l * 4);
        float s = v.x * v.x + v.y * v.y + v.z * v.z + v.w * v.w;
        #pragma unroll
        for (int m = 1; m < 32; m <<= 1) s += __shfl_xor(s, m);
        float inv = 1.0f / fmaxf(sqrtf(s), 1e-12f);
        uint2 p;
        p.x = (unsigned)f2bf(v.x * inv) | ((unsigned)f2bf(v.y * inv) << 16);
        p.y = (unsigned)f2bf(v.z * inv) | ((unsigned)f2bf(v.w * inv) << 16);
        *dst = p;
        float cnt = counts[row];
        float4 o;
        if (cnt > 0.0f) {
            int sr = class2slot[row] - 1;
            float rc = 1.0f / cnt;
            float4 av = *(const float4*)(acc + sr * D + l * 4);
            o = make_float4(av.x * rc, av.y * rc, av.z * rc, av.w * rc);
        } else {
            o = v;
        }
        *(float4*)(outw + row * D + l * 4) = o;
    } else {
        *dst = make_uint2(0u, 0u);  // pad: zero vec -> acc exactly 0 -> exp2=1, subtracted in loss
    }
}

// Main fused GEMM + exp-accumulate + (last block) loss.
// NO LDS, NO barriers in the loop: A and B fragments load direct global->VGPR
// (both L2/L1-resident). Fully unrolled 13-tile loop -> compiler pipelines
// loads across tiles with fine-grained vmcnt. 4 waves, 2x2 over 128x128 tile.
__global__ __launch_bounds__(256, 2) void main_gemm(
    const unsigned short* __restrict__ fnb, const unsigned short* __restrict__ wnb,
    const float* __restrict__ pos, float* __restrict__ sumexp,
    unsigned int* __restrict__ done, float* __restrict__ out) {
    __shared__ unsigned int sticket;
    __shared__ float red[256];
    int tid = threadIdx.x;
    int lane = tid & 63, w = tid >> 6;
    int quad = lane >> 4, l15 = lane & 15;
    int m0 = (w >> 1) * 64, n0 = (w & 1) * 64;
    int rowbase = blockIdx.y * 128;

    // A fragments: 64 rows x 128 k per wave, register-resident (16 x 16B loads).
    bf16x8 af[4][4];
    #pragma unroll
    for (int mt = 0; mt < 4; mt++) {
        int row = rowbase + m0 + mt * 16 + l15;
        #pragma unroll
        for (int ks = 0; ks < 4; ks++)
            af[mt][ks] = *(const bf16x8*)(fnb + row * D + ks * 32 + quad * 8);
    }

    const f32x4 zeroq = (f32x4){0.f, 0.f, 0.f, 0.f};
    float sums[16];
    #pragma unroll
    for (int i = 0; i < 16; i++) sums[i] = 0.0f;

    #pragma unroll
    for (int t = 0; t < TILES_PER_BLOCK; t++) {
        int ct = (blockIdx.x + t * GRIDX) * 128;   // always < 106496
        // 16 independent B-fragment loads; no barrier -> stay in flight.
        bf16x8 bf[4][4];
        #pragma unroll
        for (int nt = 0; nt < 4; nt++) {
            int col = ct + n0 + nt * 16 + l15;
            #pragma unroll
            for (int ks = 0; ks < 4; ks++)
                bf[nt][ks] = *(const bf16x8*)(wnb + col * D + ks * 32 + quad * 8);
        }
        #pragma unroll
        for (int nt = 0; nt < 4; nt++) {
            f32x4 acc[4];
            #pragma unroll
            for (int mt = 0; mt < 4; mt++)
                acc[mt] = __builtin_amdgcn_mfma_f32_16x16x32_bf16(
                    af[mt][0], bf[nt][0], zeroq, 0, 0, 0);
            #pragma unroll
            for (int ks = 1; ks < 4; ks++)
                #pragma unroll
                for (int mt = 0; mt < 4; mt++)
                    acc[mt] = __builtin_amdgcn_mfma_f32_16x16x32_bf16(
                        af[mt][ks], bf[nt][ks], acc[mt], 0, 0, 0);
            // raw units: acc = 43.28*cos -> 2^acc = e^(30 cos); no shift needed
            #pragma unroll
            for (int mt = 0; mt < 4; mt++)
                #pragma unroll
                for (int r = 0; r < 4; r++)
                    sums[mt * 4 + r] += fast_exp2(acc[mt][r]);
        }
    }

    // Reduce partials across the 16 lanes of each quad, one atomic per row per block.
    #pragma unroll
    for (int mt = 0; mt < 4; mt++) {
        #pragma unroll
        for (int r = 0; r < 4; r++) {
            float s = sums[mt * 4 + r];
            s += __shfl_xor(s, 1);
            s += __shfl_xor(s, 2);
            s += __shfl_xor(s, 4);
            s += __shfl_xor(s, 8);
            if (l15 == 0)
                atomicAdd(sumexp + rowbase + m0 + mt * 16 + quad * 4 + r, s);
        }
    }

    // Last block computes the loss. sumexp is in raw e^{logit} units and
    // includes NPAD pad columns (exactly 1.0 each) and the label column (e^p).
    __threadfence();
    if (tid == 0) sticket = atomicAdd(done, 1u);
    __syncthreads();
    if (sticket == GRID_TOTAL - 1) {
        float accv = 0.0f;
        #pragma unroll
        for (int i = 0; i < 4; i++) {
            int r = tid + i * 256;
            float se = atomicAdd(&sumexp[r], 0.0f);   // coherent device-scope read
            float p = pos[r];
            float sneg = fmaxf(se - NPAD - __expf(p), 1e-30f);
            float z = MARGIN + logf(sneg) - p;        // M + lse_neg - pos
            accv += fmaxf(z, 0.0f) + log1pf(__expf(-fabsf(z)));
        }
        red[tid] = accv;
        __syncthreads();
        for (int s = 128; s > 0; s >>= 1) {
            if (tid < s) red[tid] += red[tid + s];
            __syncthreads();
        }
        if (tid == 0) out[0] = red[0] * (1.0f / 1024.0f);
    }
}

extern "C" void kernel_launch(void* const* d_in, const int* in_sizes, int n_in,
                              void* d_out, int out_size, void* d_ws, size_t ws_size,
                              hipStream_t stream) {
    (void)in_sizes; (void)n_in; (void)out_size; (void)ws_size;
    const float* inp   = (const float*)d_in[0];
    const int*   label = (const int*)d_in[1];
    const float* wt    = (const float*)d_in[2];
    float* out = (float*)d_out;

    char* w = (char*)d_ws;
    unsigned short* fnb = (unsigned short*)(w);                // 262,144 B
    unsigned short* wnb = (unsigned short*)(w + 262144);       // 27,262,976 B (106496*128*2)
    // memset region @ 27,525,120:
    float*        sumexp     = (float*)(w + 27525120);         // 4,096 B
    float*        counts     = (float*)(w + 27529216);         // 400,384 B
    int*          class2slot = (int*)  (w + 27929600);         // 400,384 B
    float*        acc        = (float*)(w + 28329984);         // 524,288 B
    unsigned int* done       = (unsigned int*)(w + 28854272);  // 256 B
    float*        pos        = (float*)(w + 28854528);         // 4,096 B (no memset)

    hipMemsetAsync(w + 27525120, 0, 1329408, stream);

    prep_fn<<<BS / 4, 256, 0, stream>>>(inp, label, wt, fnb, counts, class2slot, acc, pos);
    prep_wn<<<NCP / 8, 256, 0, stream>>>(wt, counts, class2slot, acc, wnb, out + 1);
    main_gemm<<<dim3(GRIDX, 8), 256, 0, stream>>>(fnb, wnb, pos, sumexp, done, out);
}